// Round 1
// 139.191 us; speedup vs baseline: 1.0004x; 1.0004x over previous
//
#include <hip/hip_runtime.h>
#include <hip/hip_bf16.h>
#include <math.h>

#define NVARS 512
#define HID   16
#define TOPK  8

// ---------------- Kernel 1: routing (Q/K proj, sim, top-8, softmax) ----------
// Grid: 64 blocks x 512 threads. Wave w of block b handles row n = b*8 + w.
__global__ __launch_bounds__(512) void routing_kernel(
    const float* __restrict__ ve,   // (512,16)
    const float* __restrict__ Wq,   // (16,16)
    const float* __restrict__ bq,   // (16,)
    const float* __restrict__ Wk,   // (16,16)
    const float* __restrict__ bk,   // (16,)
    int*   __restrict__ out_idx,    // (512,8)
    float* __restrict__ out_w)      // (512,8)
{
    __shared__ float Ks[NVARS][HID + 1];   // stride 17 -> conflict-free

    const int t    = threadIdx.x;          // 0..511
    const int wave = t >> 6;               // 0..7
    const int lane = t & 63;
    const int n    = blockIdx.x * 8 + wave;  // row this wave owns

    // --- K[t][:] into LDS (each thread computes one K row) ---
    float vrow[HID];
    #pragma unroll
    for (int j = 0; j < HID; ++j) vrow[j] = ve[t * HID + j];
    #pragma unroll
    for (int h = 0; h < HID; ++h) {
        float s = bk[h];
        #pragma unroll
        for (int j = 0; j < HID; ++j) s += vrow[j] * Wk[h * HID + j];
        Ks[t][h] = s;
    }

    // --- Q[n][:] redundantly per lane (uniform loads, broadcast) ---
    float q[HID];
    #pragma unroll
    for (int j = 0; j < HID; ++j) vrow[j] = ve[n * HID + j];
    #pragma unroll
    for (int h = 0; h < HID; ++h) {
        float s = bq[h];
        #pragma unroll
        for (int j = 0; j < HID; ++j) s += vrow[j] * Wq[h * HID + j];
        q[h] = s;
    }

    __syncthreads();

    // --- sims for m = i*64 + lane (8 per lane = full 512 per wave) ---
    float vals[8];
    #pragma unroll
    for (int i = 0; i < 8; ++i) {
        const int m = i * 64 + lane;
        float s = 0.f;
        #pragma unroll
        for (int h = 0; h < HID; ++h) s += q[h] * Ks[m][h];
        vals[i] = (m == n) ? -1.0e9f : s;
    }

    // --- 8 rounds of wave-wide argmax (top-8) ---
    float mx = 0.f, my_val = 0.f, sum_exp = 0.f;
    int my_idx = 0;
    #pragma unroll
    for (int r = 0; r < TOPK; ++r) {
        float bv = vals[0];
        int   bi = lane;                    // m = 0*64 + lane
        #pragma unroll
        for (int i = 1; i < 8; ++i) {
            const int m = i * 64 + lane;
            if (vals[i] > bv) { bv = vals[i]; bi = m; }   // strict > keeps lowest m on tie
        }
        #pragma unroll
        for (int off = 32; off >= 1; off >>= 1) {
            const float ov = __shfl_xor(bv, off);
            const int   oi = __shfl_xor(bi, off);
            if (ov > bv || (ov == bv && oi < bi)) { bv = ov; bi = oi; }
        }
        // all lanes now hold round-r winner (bv, bi)
        if (r == 0) mx = bv;
        sum_exp += __expf(bv - mx);
        if (lane == r) { my_val = bv; my_idx = bi; }
        // owner lane retires the winner
        if ((bi & 63) == lane) {
            const int slot = bi >> 6;
            #pragma unroll
            for (int i = 0; i < 8; ++i)
                if (slot == i) vals[i] = -3.4e38f;
        }
    }

    if (lane < TOPK) {
        out_idx[n * TOPK + lane] = my_idx;
        out_w[n * TOPK + lane]   = __expf(my_val - mx) / sum_exp;
    }
}

// ---------------- Kernel 2: gather-weighted sum over rows --------------------
// Evolution of the R2 winner (139.1 us total). Structure preserved: 1024
// blocks x 512 threads, 32 rows/block, transposed LDS tile so one random
// gather serves multiple rows, double-buffered.
// R5 changes (theory: the 16 __syncthreads/block each emit
// "s_waitcnt vmcnt(0) lgkmcnt(0); s_barrier", force-draining the prefetch
// global loads INSIDE the same group they were issued -> double-buffer's
// latency hiding defeated):
//   (a) 8 rows/group (LDS [2][2][512] float4 = 32 KB; still 4 blocks/CU by
//       the 32-wave limit) -> 4 groups/block.
//   (b) ONE raw barrier per group: s_waitcnt lgkmcnt(0) + s_barrier,
//       memory-clobber fenced on both sides. Only LDS ordering is required
//       at the barrier (ds_writes visible; prior group's ds_read gathers are
//       lgkm ops retired by each wave's own lgkmcnt(0) before it arrives).
//       Global prefetch loads are never drained at a barrier; the compiler
//       inserts counted vmcnt(N) where v[] is consumed (next ds_write).
//       Single barrier per group is safe with double buffering:
//       reads(g) < barrier(g+1) < writes(g+2) to the same buffer.
// Known-worse (prior session): wave-private LDS/256thr (occupancy 20 vs 32
// waves/CU), nontemporal + long-lived prefetch regs.
__global__ __launch_bounds__(512) void apply_kernel(
    const float* __restrict__ x,     // (32768, 512)
    const int*   __restrict__ gidx,  // (512, 8)
    const float* __restrict__ gw,    // (512, 8)
    float*       __restrict__ out)   // (32768, 512)
{
    __shared__ float4 xs[2][2][NVARS];  // [buf][rowhalf][col] : 32 KB

    const int t = threadIdx.x;       // thread t owns column t (all rows)
    const int4   i0 = ((const int4*)gidx)[2 * t + 0];
    const int4   i1 = ((const int4*)gidx)[2 * t + 1];
    const float4 w0 = ((const float4*)gw)[2 * t + 0];
    const float4 w1 = ((const float4*)gw)[2 * t + 1];

    const long base = (long)blockIdx.x * 32;

    // preload group 0: column t of rows base..base+7 (coalesced dword loads)
    const float* xp = x + base * NVARS + t;
    float v0 = xp[0 * NVARS];
    float v1 = xp[1 * NVARS];
    float v2 = xp[2 * NVARS];
    float v3 = xp[3 * NVARS];
    float v4 = xp[4 * NVARS];
    float v5 = xp[5 * NVARS];
    float v6 = xp[6 * NVARS];
    float v7 = xp[7 * NVARS];

    #pragma unroll 1
    for (int g = 0; g < 4; ++g) {
        float4 (*buf)[NVARS] = xs[g & 1];
        buf[0][t] = make_float4(v0, v1, v2, v3);   // conflict-free b128 writes
        buf[1][t] = make_float4(v4, v5, v6, v7);

        // issue next group's prefetch BEFORE the barrier -- nothing drains
        // vmcnt at the barrier anymore, so these flow across it.
        if (g < 3) {
            const float* xn = x + (base + 8 * (g + 1)) * NVARS + t;
            v0 = xn[0 * NVARS];
            v1 = xn[1 * NVARS];
            v2 = xn[2 * NVARS];
            v3 = xn[3 * NVARS];
            v4 = xn[4 * NVARS];
            v5 = xn[5 * NVARS];
            v6 = xn[6 * NVARS];
            v7 = xn[7 * NVARS];
        }

        // lgkm-only barrier: ds_writes of this group done + this wave's
        // gathers of group g-1 retired; do NOT drain vmcnt.
        asm volatile("s_waitcnt lgkmcnt(0)" ::: "memory");
        __builtin_amdgcn_s_barrier();
        asm volatile("" ::: "memory");   // no LDS op may hoist above barrier

        float a0 = 0.f, a1 = 0.f, a2 = 0.f, a3 = 0.f;
        float a4 = 0.f, a5 = 0.f, a6 = 0.f, a7 = 0.f;
        float4 c0, c1;
#define GATH(II, WW)                                                     \
        c0 = buf[0][II]; c1 = buf[1][II];                                \
        a0 += c0.x * WW; a1 += c0.y * WW; a2 += c0.z * WW; a3 += c0.w * WW; \
        a4 += c1.x * WW; a5 += c1.y * WW; a6 += c1.z * WW; a7 += c1.w * WW;
        GATH(i0.x, w0.x)
        GATH(i0.y, w0.y)
        GATH(i0.z, w0.z)
        GATH(i0.w, w0.w)
        GATH(i1.x, w1.x)
        GATH(i1.y, w1.y)
        GATH(i1.z, w1.z)
        GATH(i1.w, w1.w)
#undef GATH

        float* o = out + (base + 8 * g) * NVARS + t;
        o[0 * NVARS] = a0;
        o[1 * NVARS] = a1;
        o[2 * NVARS] = a2;
        o[3 * NVARS] = a3;
        o[4 * NVARS] = a4;
        o[5 * NVARS] = a5;
        o[6 * NVARS] = a6;
        o[7 * NVARS] = a7;
        // no trailing barrier: next iteration's ds_writes target the other
        // buffer; same-buffer WAR is separated by the next barrier.
    }
}

extern "C" void kernel_launch(void* const* d_in, const int* in_sizes, int n_in,
                              void* d_out, int out_size, void* d_ws, size_t ws_size,
                              hipStream_t stream) {
    const float* x  = (const float*)d_in[0];   // (8,4096,512)
    const float* ve = (const float*)d_in[1];   // (512,16)
    const float* Wq = (const float*)d_in[2];   // (16,16)
    const float* bq = (const float*)d_in[3];   // (16,)
    const float* Wk = (const float*)d_in[4];   // (16,16)
    const float* bk = (const float*)d_in[5];   // (16,)
    float* out = (float*)d_out;

    int*   idx_ws = (int*)d_ws;
    float* w_ws   = (float*)((char*)d_ws + NVARS * TOPK * sizeof(int));

    routing_kernel<<<64, 512, 0, stream>>>(ve, Wq, bq, Wk, bk, idx_ws, w_ws);
    apply_kernel<<<1024, 512, 0, stream>>>(x, idx_ws, w_ws, out);
}